// Round 6
// baseline (120.825 us; speedup 1.0000x reference)
//
#include <hip/hip_runtime.h>

// PointPillars scatter: canvas[b, c, y, x] = feat[n, c] where coords[n] = (b, _, y, x)
// R6: sequential plane-segment writes + amortized map reads.
//   K1: map[:] = -1
//   K2: map[b*NY*NX + y*NX + x] = n       (collision-free per problem spec)
//   K3: block = (b, channel-quad, quarter-plane): 8*16*4 = 512 blocks (2/CU
//       exact). Each block sweeps a contiguous 40000-cell segment, writing 4
//       contiguous 160KB plane streams. One map int4 (16B) -> 64B of stores;
//       one fvec4 gather feat[m][c0..c0+3] serves all 4 channels. Map slice
//       L2-resident; gathers exec-masked (7.5% lanes). Map prefetch depth 1.

#define NXD 400
#define NYD 400
#define CCH 64
#define NXY (NXD * NYD)      // 160000 cells/sample
#define QCELLS 40000         // cells per quarter-plane segment
#define QCHUNK (QCELLS / 4)  // 10000 16B chunks per segment

typedef float fvec4 __attribute__((ext_vector_type(4)));
typedef int   ivec4 __attribute__((ext_vector_type(4)));

__global__ void pps_init_map(ivec4* __restrict__ map4, int total4) {
    int i = blockIdx.x * blockDim.x + threadIdx.x;
    int stride = gridDim.x * blockDim.x;
    ivec4 neg1 = {-1, -1, -1, -1};
    for (; i < total4; i += stride)
        __builtin_nontemporal_store(neg1, map4 + i);
}

__global__ void pps_build_map(const int* __restrict__ coords, int* __restrict__ map, int n) {
    int i = blockIdx.x * blockDim.x + threadIdx.x;
    if (i >= n) return;
    ivec4 c4 = *(const ivec4*)(coords + i * 4);   // (b, _, y, x)
    map[c4.x * NXY + c4.z * NXD + c4.w] = i;
}

__global__ __launch_bounds__(256) void pps_plane_quad(const float* __restrict__ feat,
                                                      const int* __restrict__ map,
                                                      float* __restrict__ out) {
    // blockIdx.x = ((b * 16 + cq) * 4 + quarter)
    int bid = blockIdx.x;
    int quarter = bid & 3;
    int cq      = (bid >> 2) & 15;
    int b       = bid >> 6;
    int c0      = cq * 4;

    int s_base = quarter * QCELLS;
    const int* mrow = map + b * NXY + s_base;
    float* o0 = out + ((size_t)(b * CCH + c0 + 0)) * NXY + s_base;
    float* o1 = o0 + NXY;
    float* o2 = o1 + NXY;
    float* o3 = o2 + NXY;

    int t = threadIdx.x;

    // prefetch first map chunk
    ivec4 m = *(const ivec4*)(mrow + t * 4);

    const fvec4 zero = {0.f, 0.f, 0.f, 0.f};

    for (int j = t; j < QCHUNK; j += 256) {
        int s4 = j * 4;
        ivec4 mc = m;
        // prefetch next chunk's map entries before the dependent work
        int jn = j + 256;
        if (jn < QCHUNK) m = *(const ivec4*)(mrow + jn * 4);

        // masked gathers: feat[m][c0..c0+3] is one contiguous fvec4
        fvec4 g0 = zero, g1 = zero, g2 = zero, g3 = zero;
        if (mc.x >= 0) g0 = *(const fvec4*)(feat + (size_t)mc.x * CCH + c0);
        if (mc.y >= 0) g1 = *(const fvec4*)(feat + (size_t)mc.y * CCH + c0);
        if (mc.z >= 0) g2 = *(const fvec4*)(feat + (size_t)mc.z * CCH + c0);
        if (mc.w >= 0) g3 = *(const fvec4*)(feat + (size_t)mc.w * CCH + c0);

        // transpose: plane c0+k at cells s4..s4+3 gets {g0[k], g1[k], g2[k], g3[k]}
        fvec4 v0 = {g0.x, g1.x, g2.x, g3.x};
        fvec4 v1 = {g0.y, g1.y, g2.y, g3.y};
        fvec4 v2 = {g0.z, g1.z, g2.z, g3.z};
        fvec4 v3 = {g0.w, g1.w, g2.w, g3.w};
        __builtin_nontemporal_store(v0, (fvec4*)(o0 + s4));
        __builtin_nontemporal_store(v1, (fvec4*)(o1 + s4));
        __builtin_nontemporal_store(v2, (fvec4*)(o2 + s4));
        __builtin_nontemporal_store(v3, (fvec4*)(o3 + s4));
    }
}

extern "C" void kernel_launch(void* const* d_in, const int* in_sizes, int n_in,
                              void* d_out, int out_size, void* d_ws, size_t ws_size,
                              hipStream_t stream) {
    const float* feat  = (const float*)d_in[0];   // [N, 64] fp32
    const int* coords  = (const int*)d_in[1];     // [N, 4] int32 (b, _, y, x)
    float* out         = (float*)d_out;           // [B, 64, NY, NX] fp32

    const int n_pillars = in_sizes[1] / 4;
    const int batch     = out_size / (CCH * NXY);
    const int total_pos = batch * NXY;            // 1.28M cells

    int* map = (int*)d_ws;                        // batch*NXY*4 = 5.12 MB

    // K1: reset map every call (d_ws not re-poisoned between replays)
    pps_init_map<<<1024, 256, 0, stream>>>((ivec4*)map, total_pos / 4);

    // K2: scatter pillar indices into the map
    pps_build_map<<<(n_pillars + 255) / 256, 256, 0, stream>>>(coords, map, n_pillars);

    // K3: one block per (b, channel-quad, quarter-plane)
    {
        int nblocks = batch * 16 * 4;             // 512
        pps_plane_quad<<<nblocks, 256, 0, stream>>>(feat, map, out);
    }
}

// Round 7
// 94.395 us; speedup vs baseline: 1.2800x; 1.2800x over previous
//
#include <hip/hip_runtime.h>

// PointPillars scatter: canvas[b, c, y, x] = feat[n, c] where coords[n] = (b, _, y, x)
// R7: scatter->gather inversion + LDS-staged feat rows (read feat ONCE from HBM).
//   K1: map[:] = -1
//   K2: map[b*NY*NX + y*NX + x] = n        (collision-free per problem spec)
//   K3: block = 1000 cells of one sample (1280 blocks, 5/CU, ~16 waves/CU).
//       Phase A: map int4 once -> compact occupied cells (LDS atomics) ->
//                cooperative coalesced load of each occupied feat row (256B)
//                into LDS exactly once.  Phase B: c-quad sweep from LDS,
//                4x4 transpose, nontemporal fvec4 stores (R2/R4's proven
//                write shape).  Overflow >128 rows: direct-gather fallback.

#define NXD 400
#define NYD 400
#define CCH 64
#define NXY (NXD * NYD)    // 160000 cells/sample
#define CPB 1000           // cells per block (divides NXY; %4==0)
#define BPS (NXY / CPB)    // 160 blocks per sample
#define MAXROWS 128        // LDS row capacity (expected ~75, 6-sigma safe + fallback)
#define RSTRIDE 68         // floats per LDS row (272B: 16B-aligned, breaks bank align)

typedef float fvec4 __attribute__((ext_vector_type(4)));
typedef int   ivec4 __attribute__((ext_vector_type(4)));

__global__ void pps_init_map(ivec4* __restrict__ map4, int total4) {
    int i = blockIdx.x * blockDim.x + threadIdx.x;
    int stride = gridDim.x * blockDim.x;
    ivec4 neg1 = {-1, -1, -1, -1};
    for (; i < total4; i += stride)
        __builtin_nontemporal_store(neg1, map4 + i);
}

__global__ void pps_build_map(const int* __restrict__ coords, int* __restrict__ map, int n) {
    int i = blockIdx.x * blockDim.x + threadIdx.x;
    if (i >= n) return;
    ivec4 c4 = *(const ivec4*)(coords + i * 4);   // (b, _, y, x)
    map[c4.x * NXY + c4.z * NXD + c4.w] = i;
}

__global__ __launch_bounds__(256) void pps_gather_lds(const float* __restrict__ feat,
                                                      const int* __restrict__ map,
                                                      float* __restrict__ out) {
    __shared__ float lfeat[MAXROWS][RSTRIDE];   // 34816 B
    __shared__ int   c2s[CPB];                  //  4000 B: slot | -1 empty | ~m overflow
    __shared__ int   srow[MAXROWS];             //   512 B: pillar index per slot
    __shared__ int   cnt;

    const int bid = blockIdx.x;
    const int b   = bid / BPS;
    const int s0  = (bid - b * BPS) * CPB;
    const int t   = threadIdx.x;

    if (t == 0) cnt = 0;
    __syncthreads();

    // ---- Phase A1: read map once, classify cells, compact occupied ----
    ivec4 m4 = {-1, -1, -1, -1};
    if (t < CPB / 4) {
        m4 = *(const ivec4*)(map + b * NXY + s0 + t * 4);   // 16B coalesced
        int cell = t * 4;
        int mk[4] = {m4.x, m4.y, m4.z, m4.w};
        #pragma unroll
        for (int k = 0; k < 4; ++k) {
            int v = -1;
            if (mk[k] >= 0) {
                int slot = atomicAdd(&cnt, 1);
                if (slot < MAXROWS) { srow[slot] = mk[k]; v = slot; }
                else v = ~mk[k];                 // overflow: remember pillar id
            }
            c2s[cell + k] = v;
        }
    }
    __syncthreads();

    // ---- Phase A2: cooperative coalesced load of occupied rows into LDS ----
    int nrows = min(cnt, MAXROWS);
    {
        int lane = t & 15;                       // 16 lanes per row, fvec4 each
        for (int r = (t >> 4); r < nrows; r += 16) {
            *(fvec4*)&lfeat[r][lane * 4] =
                *(const fvec4*)(feat + (size_t)srow[r] * CCH + lane * 4);
        }
    }
    __syncthreads();

    // ---- Phase B: c-quad sweep from LDS, transpose, nt stores ----
    if (t >= CPB / 4) return;
    const int cell = t * 4;
    ivec4 sl = *(const ivec4*)&c2s[cell];        // slots for this thread's 4 cells
    float* ob = out + (size_t)(b * CCH) * NXY + (s0 + cell);

    const fvec4 zero = {0.f, 0.f, 0.f, 0.f};

    #pragma unroll 4
    for (int cq = 0; cq < 16; ++cq) {
        int c0 = cq * 4;
        fvec4 g0 = zero, g1 = zero, g2 = zero, g3 = zero;
        if (sl.x >= 0)      g0 = *(const fvec4*)&lfeat[sl.x][c0];
        else if (sl.x < -1) g0 = *(const fvec4*)(feat + (size_t)(~sl.x) * CCH + c0);
        if (sl.y >= 0)      g1 = *(const fvec4*)&lfeat[sl.y][c0];
        else if (sl.y < -1) g1 = *(const fvec4*)(feat + (size_t)(~sl.y) * CCH + c0);
        if (sl.z >= 0)      g2 = *(const fvec4*)&lfeat[sl.z][c0];
        else if (sl.z < -1) g2 = *(const fvec4*)(feat + (size_t)(~sl.z) * CCH + c0);
        if (sl.w >= 0)      g3 = *(const fvec4*)&lfeat[sl.w][c0];
        else if (sl.w < -1) g3 = *(const fvec4*)(feat + (size_t)(~sl.w) * CCH + c0);

        // transpose: plane c0+k at these 4 cells gets {g0[k], g1[k], g2[k], g3[k]}
        fvec4 v0 = {g0.x, g1.x, g2.x, g3.x};
        fvec4 v1 = {g0.y, g1.y, g2.y, g3.y};
        fvec4 v2 = {g0.z, g1.z, g2.z, g3.z};
        fvec4 v3 = {g0.w, g1.w, g2.w, g3.w};
        __builtin_nontemporal_store(v0, (fvec4*)(ob + (size_t)(c0 + 0) * NXY));
        __builtin_nontemporal_store(v1, (fvec4*)(ob + (size_t)(c0 + 1) * NXY));
        __builtin_nontemporal_store(v2, (fvec4*)(ob + (size_t)(c0 + 2) * NXY));
        __builtin_nontemporal_store(v3, (fvec4*)(ob + (size_t)(c0 + 3) * NXY));
    }
}

extern "C" void kernel_launch(void* const* d_in, const int* in_sizes, int n_in,
                              void* d_out, int out_size, void* d_ws, size_t ws_size,
                              hipStream_t stream) {
    const float* feat  = (const float*)d_in[0];   // [N, 64] fp32
    const int* coords  = (const int*)d_in[1];     // [N, 4] int32 (b, _, y, x)
    float* out         = (float*)d_out;           // [B, 64, NY, NX] fp32

    const int n_pillars = in_sizes[1] / 4;
    const int batch     = out_size / (CCH * NXY);
    const int total_pos = batch * NXY;            // 1.28M cells

    int* map = (int*)d_ws;                        // batch*NXY*4 = 5.12 MB

    // K1: reset map every call (d_ws not re-poisoned between replays)
    pps_init_map<<<1024, 256, 0, stream>>>((ivec4*)map, total_pos / 4);

    // K2: scatter pillar indices into the map
    pps_build_map<<<(n_pillars + 255) / 256, 256, 0, stream>>>(coords, map, n_pillars);

    // K3: LDS-staged gather pass, 1280 uniform blocks
    pps_gather_lds<<<batch * BPS, 256, 0, stream>>>(feat, map, out);
}